// Round 9
// baseline (2598.456 us; speedup 1.0000x reference)
//
#include <hip/hip_runtime.h>
#include <hip/hip_bf16.h>

#define NN 100000
#define NE 640000
#define NG 512
#define NIN 64
#define EIN 16
#define H 128
#define H2 256
#define NL 4

#define FMA4(acc, s, wv)                      \
    acc.x = fmaf(s, wv.x, acc.x);             \
    acc.y = fmaf(s, wv.y, acc.y);             \
    acc.z = fmaf(s, wv.z, acc.z);             \
    acc.w = fmaf(s, wv.w, acc.w)

// ---------------- node projection: X = relu(x @ node_w + node_b) ----------------
__global__ __launch_bounds__(256) void k_node_proj(const float* __restrict__ x,
                                                   const float* __restrict__ W,
                                                   const float* __restrict__ b,
                                                   float* __restrict__ h) {
    __shared__ float sW[NIN * H];  // 32 KB
    int tid = threadIdx.x;
    for (int i = tid; i < NIN * H; i += 256) sW[i] = W[i];
    __syncthreads();
    int c = tid & 127, half = tid >> 7;
    for (int node = blockIdx.x * 2 + half; node < NN; node += gridDim.x * 2) {
        const float* xr = x + (size_t)node * NIN;
        float acc = b[c];
#pragma unroll
        for (int k = 0; k < NIN; ++k) acc = fmaf(xr[k], sW[k * H + c], acc);
        h[(size_t)node * H + c] = fmaxf(acc, 0.f);
    }
}

// ---------------- CSR build ----------------
__global__ __launch_bounds__(256) void k_hist(const int* __restrict__ dst, int* __restrict__ deg) {
    int e = blockIdx.x * 256 + threadIdx.x;
    if (e < NE) atomicAdd(&deg[dst[e]], 1);
}

__global__ __launch_bounds__(256) void k_scan1(const int* __restrict__ deg, int* __restrict__ ex,
                                               int* __restrict__ totals) {
    __shared__ int s[256];
    int t = threadIdx.x, b = blockIdx.x;
    int base = b * 1024 + t * 4;
    int v0 = (base + 0 < NN) ? deg[base + 0] : 0;
    int v1 = (base + 1 < NN) ? deg[base + 1] : 0;
    int v2 = (base + 2 < NN) ? deg[base + 2] : 0;
    int v3 = (base + 3 < NN) ? deg[base + 3] : 0;
    int t0 = v0, t1 = t0 + v1, t2 = t1 + v2, tsum = t2 + v3;
    s[t] = tsum;
    __syncthreads();
#pragma unroll
    for (int d = 1; d < 256; d <<= 1) {
        int add = (t >= d) ? s[t - d] : 0;
        __syncthreads();
        s[t] += add;
        __syncthreads();
    }
    int excl = s[t] - tsum;
    ex[base + 0] = excl;
    ex[base + 1] = excl + t0;
    ex[base + 2] = excl + t1;
    ex[base + 3] = excl + t2;
    if (t == 255) totals[b] = s[t];
}

__global__ void k_scan2(const int* __restrict__ totals, int* __restrict__ boff) {
    __shared__ int s[256];
    int t = threadIdx.x;
    int v = (t < 98) ? totals[t] : 0;
    s[t] = v;
    __syncthreads();
#pragma unroll
    for (int d = 1; d < 256; d <<= 1) {
        int add = (t >= d) ? s[t - d] : 0;
        __syncthreads();
        s[t] += add;
        __syncthreads();
    }
    if (t < 98) boff[t] = s[t] - v;
}

__global__ __launch_bounds__(256) void k_scan3(const int* __restrict__ ex, const int* __restrict__ boff,
                                               int* __restrict__ rowptr, int* __restrict__ cursor) {
    int i = blockIdx.x * 256 + threadIdx.x;
    if (i < NN) {
        int r = ex[i] + boff[i >> 10];
        rowptr[i] = r;
        cursor[i] = r;
    }
    if (i == 0) rowptr[NN] = NE;
}

// scatter: erec[p] = (src, dst, eid, 0) — one 16B record per edge, dst-sorted
__global__ __launch_bounds__(256) void k_scatter(const int* __restrict__ src,
                                                 const int* __restrict__ dst,
                                                 int* __restrict__ cursor,
                                                 int4* __restrict__ erec) {
    int e = blockIdx.x * 256 + threadIdx.x;
    if (e < NE) {
        int d = dst[e];
        int p = atomicAdd(&cursor[d], 1);
        erec[p] = make_int4(src[e], d, e, 0);
    }
}

__global__ void k_prm_id(float* __restrict__ prm) {
    int c = threadIdx.x;  // 128
    prm[c] = 1.f;
    prm[H + c] = 0.f;
}

// ------- edge-parallel aggregate over dst-sorted records; flush on dst change -------
__global__ __launch_bounds__(256) void k_agg(const int4* __restrict__ erec,
                                             const float* __restrict__ ea,
                                             const float* __restrict__ We,
                                             const float* __restrict__ be,
                                             const float* __restrict__ hsrc,
                                             const float* __restrict__ prm,
                                             float* __restrict__ agg) {
    int tid = threadIdx.x;
    int c = tid & 127, grp = tid >> 7;
    float wcol[EIN];
#pragma unroll
    for (int k = 0; k < EIN; ++k) wcol[k] = We[k * H + c];
    float bec = be[c], sc = prm[c], sh = prm[H + c];
    const float4* ea4 = (const float4*)ea;
    int base = (blockIdx.x * 2 + grp) * 32;  // 10000 blocks * 2 groups * 32 edges = NE
    int cur = erec[base].y;
    float acc = 0.f;
#pragma unroll 2
    for (int i0 = 0; i0 < 32; i0 += 4) {
        int4 r0 = erec[base + i0 + 0];
        int4 r1 = erec[base + i0 + 1];
        int4 r2 = erec[base + i0 + 2];
        int4 r3 = erec[base + i0 + 3];
        float hv0 = hsrc[(size_t)r0.x * H + c];
        float hv1 = hsrc[(size_t)r1.x * H + c];
        float hv2 = hsrc[(size_t)r2.x * H + c];
        float hv3 = hsrc[(size_t)r3.x * H + c];
        float4 a0 = ea4[(size_t)r0.z * 4 + 0], a1 = ea4[(size_t)r0.z * 4 + 1],
               a2 = ea4[(size_t)r0.z * 4 + 2], a3 = ea4[(size_t)r0.z * 4 + 3];
        float4 b0 = ea4[(size_t)r1.z * 4 + 0], b1 = ea4[(size_t)r1.z * 4 + 1],
               b2 = ea4[(size_t)r1.z * 4 + 2], b3 = ea4[(size_t)r1.z * 4 + 3];
        float4 c0 = ea4[(size_t)r2.z * 4 + 0], c1 = ea4[(size_t)r2.z * 4 + 1],
               c2 = ea4[(size_t)r2.z * 4 + 2], c3 = ea4[(size_t)r2.z * 4 + 3];
        float4 d0 = ea4[(size_t)r3.z * 4 + 0], d1 = ea4[(size_t)r3.z * 4 + 1],
               d2 = ea4[(size_t)r3.z * 4 + 2], d3 = ea4[(size_t)r3.z * 4 + 3];

#define EPROJ(pp, e0, e1, e2, e3)                                              \
        {                                                                      \
            pp = bec;                                                          \
            pp = fmaf(e0.x, wcol[0], pp);  pp = fmaf(e0.y, wcol[1], pp);       \
            pp = fmaf(e0.z, wcol[2], pp);  pp = fmaf(e0.w, wcol[3], pp);       \
            pp = fmaf(e1.x, wcol[4], pp);  pp = fmaf(e1.y, wcol[5], pp);       \
            pp = fmaf(e1.z, wcol[6], pp);  pp = fmaf(e1.w, wcol[7], pp);       \
            pp = fmaf(e2.x, wcol[8], pp);  pp = fmaf(e2.y, wcol[9], pp);       \
            pp = fmaf(e2.z, wcol[10], pp); pp = fmaf(e2.w, wcol[11], pp);      \
            pp = fmaf(e3.x, wcol[12], pp); pp = fmaf(e3.y, wcol[13], pp);      \
            pp = fmaf(e3.z, wcol[14], pp); pp = fmaf(e3.w, wcol[15], pp);      \
            pp = fmaxf(pp, 0.f);                                               \
        }
        float p0, p1, p2, p3;
        EPROJ(p0, a0, a1, a2, a3)
        EPROJ(p1, b0, b1, b2, b3)
        EPROJ(p2, c0, c1, c2, c3)
        EPROJ(p3, d0, d1, d2, d3)
#undef EPROJ
        float m0 = fmaxf(fmaxf(fmaf(sc, hv0, sh), 0.f) + p0, 0.f);
        float m1 = fmaxf(fmaxf(fmaf(sc, hv1, sh), 0.f) + p1, 0.f);
        float m2 = fmaxf(fmaxf(fmaf(sc, hv2, sh), 0.f) + p2, 0.f);
        float m3 = fmaxf(fmaxf(fmaf(sc, hv3, sh), 0.f) + p3, 0.f);
        if (r0.y != cur) { atomicAdd(&agg[(size_t)cur * H + c], acc); acc = 0.f; cur = r0.y; }
        acc += m0;
        if (r1.y != cur) { atomicAdd(&agg[(size_t)cur * H + c], acc); acc = 0.f; cur = r1.y; }
        acc += m1;
        if (r2.y != cur) { atomicAdd(&agg[(size_t)cur * H + c], acc); acc = 0.f; cur = r2.y; }
        acc += m2;
        if (r3.y != cur) { atomicAdd(&agg[(size_t)cur * H + c], acc); acc = 0.f; cur = r3.y; }
        acc += m3;
    }
    atomicAdd(&agg[(size_t)cur * H + c], acc);
}

// ---- MLP per 32-node tile, 8-col register blocking; z2 written in-place into agg ----
#define STP 65  // st row stride in float4 (padded: 64+1)
__global__ __launch_bounds__(256) void k_mlp(const float* __restrict__ hsrc,
                                             const float* __restrict__ prm,
                                             float* __restrict__ agg,  // in: agg, out: z2
                                             const float* __restrict__ w1,
                                             const float* __restrict__ b1,
                                             const float* __restrict__ w2,
                                             const float* __restrict__ b2,
                                             float* __restrict__ stats) {
    __shared__ float4 sz4[32 * 32];      // 16 KB  [node][32 f4]
    __shared__ float4 st4[32 * STP];     // 33.3 KB [node][65 f4 padded]
    __shared__ float ls[2 * H];          // 1 KB
    int tid = threadIdx.x;
    int base = blockIdx.x * 32;  // 3125 * 32 == 100000
    ls[tid] = 0.f;

    // phase 1: z = relu(sc*h+sh) + agg -> LDS
    const float4* X4 = (const float4*)hsrc;
    const float4* A4 = (const float4*)agg;
#pragma unroll
    for (int it = 0; it < 4; ++it) {
        int chunk = tid + it * 256;  // 0..1023
        int n = chunk >> 5;
        int c4 = chunk & 31;
        const float4 sc4 = *(const float4*)&prm[c4 * 4];
        const float4 sh4 = *(const float4*)&prm[H + c4 * 4];
        size_t gi = (size_t)(base + n) * 32 + c4;
        float4 hv = X4[gi], av = A4[gi];
        float4 z;
        z.x = fmaxf(fmaf(sc4.x, hv.x, sh4.x), 0.f) + av.x;
        z.y = fmaxf(fmaf(sc4.y, hv.y, sh4.y), 0.f) + av.y;
        z.z = fmaxf(fmaf(sc4.z, hv.z, sh4.z), 0.f) + av.z;
        z.w = fmaxf(fmaf(sc4.w, hv.w, sh4.w), 0.f) + av.w;
        sz4[chunk] = z;
    }
    __syncthreads();

    // phase 2: t = relu(z @ w1 + b1). thread: 8 cols (f4 pair cg*2,cg*2+1), 4 nodes
    {
        int cg = tid & 31, ng = tid >> 5;
        const float4* W14 = (const float4*)w1;  // [128][64] f4
        float4 accA[4], accB[4];
        float4 bA = ((const float4*)b1)[cg * 2], bB = ((const float4*)b1)[cg * 2 + 1];
#pragma unroll
        for (int n = 0; n < 4; ++n) { accA[n] = bA; accB[n] = bB; }
        for (int k0 = 0; k0 < H; k0 += 4) {
            float4 w0a = W14[(k0 + 0) * 64 + cg * 2], w0b = W14[(k0 + 0) * 64 + cg * 2 + 1];
            float4 w1a = W14[(k0 + 1) * 64 + cg * 2], w1b = W14[(k0 + 1) * 64 + cg * 2 + 1];
            float4 w2a = W14[(k0 + 2) * 64 + cg * 2], w2b = W14[(k0 + 2) * 64 + cg * 2 + 1];
            float4 w3a = W14[(k0 + 3) * 64 + cg * 2], w3b = W14[(k0 + 3) * 64 + cg * 2 + 1];
#pragma unroll
            for (int n = 0; n < 4; ++n) {
                float4 zv = sz4[(ng * 4 + n) * 32 + (k0 >> 2)];
                FMA4(accA[n], zv.x, w0a); FMA4(accB[n], zv.x, w0b);
                FMA4(accA[n], zv.y, w1a); FMA4(accB[n], zv.y, w1b);
                FMA4(accA[n], zv.z, w2a); FMA4(accB[n], zv.z, w2b);
                FMA4(accA[n], zv.w, w3a); FMA4(accB[n], zv.w, w3b);
            }
        }
#pragma unroll
        for (int n = 0; n < 4; ++n) {
            float4 rA, rB;
            rA.x = fmaxf(accA[n].x, 0.f); rA.y = fmaxf(accA[n].y, 0.f);
            rA.z = fmaxf(accA[n].z, 0.f); rA.w = fmaxf(accA[n].w, 0.f);
            rB.x = fmaxf(accB[n].x, 0.f); rB.y = fmaxf(accB[n].y, 0.f);
            rB.z = fmaxf(accB[n].z, 0.f); rB.w = fmaxf(accB[n].w, 0.f);
            st4[(ng * 4 + n) * STP + cg * 2] = rA;
            st4[(ng * 4 + n) * STP + cg * 2 + 1] = rB;
        }
    }
    __syncthreads();

    // phase 3: z2 = t @ w2 + b2. thread: 8 cols (f4 pair cg*2,cg*2+1), 2 nodes
    {
        int cg = tid & 15, ng = tid >> 4;
        const float4* W24 = (const float4*)w2;  // [256][32] f4
        float4 aA[2], aB[2];
        float4 bA = ((const float4*)b2)[cg * 2], bB = ((const float4*)b2)[cg * 2 + 1];
#pragma unroll
        for (int n = 0; n < 2; ++n) { aA[n] = bA; aB[n] = bB; }
        for (int j0 = 0; j0 < H2; j0 += 4) {
            float4 w0a = W24[(j0 + 0) * 32 + cg * 2], w0b = W24[(j0 + 0) * 32 + cg * 2 + 1];
            float4 w1a = W24[(j0 + 1) * 32 + cg * 2], w1b = W24[(j0 + 1) * 32 + cg * 2 + 1];
            float4 w2a = W24[(j0 + 2) * 32 + cg * 2], w2b = W24[(j0 + 2) * 32 + cg * 2 + 1];
            float4 w3a = W24[(j0 + 3) * 32 + cg * 2], w3b = W24[(j0 + 3) * 32 + cg * 2 + 1];
#pragma unroll
            for (int n = 0; n < 2; ++n) {
                float4 tv = st4[(ng * 2 + n) * STP + (j0 >> 2)];
                FMA4(aA[n], tv.x, w0a); FMA4(aB[n], tv.x, w0b);
                FMA4(aA[n], tv.y, w1a); FMA4(aB[n], tv.y, w1b);
                FMA4(aA[n], tv.z, w2a); FMA4(aB[n], tv.z, w2b);
                FMA4(aA[n], tv.w, w3a); FMA4(aB[n], tv.w, w3b);
            }
        }
        float4* O4 = (float4*)agg;
        float4 svA = {0, 0, 0, 0}, svB = {0, 0, 0, 0}, qvA = {0, 0, 0, 0}, qvB = {0, 0, 0, 0};
#pragma unroll
        for (int n = 0; n < 2; ++n) {
            O4[(size_t)(base + ng * 2 + n) * 32 + cg * 2] = aA[n];
            O4[(size_t)(base + ng * 2 + n) * 32 + cg * 2 + 1] = aB[n];
            svA.x += aA[n].x; svA.y += aA[n].y; svA.z += aA[n].z; svA.w += aA[n].w;
            svB.x += aB[n].x; svB.y += aB[n].y; svB.z += aB[n].z; svB.w += aB[n].w;
            qvA.x += aA[n].x * aA[n].x; qvA.y += aA[n].y * aA[n].y;
            qvA.z += aA[n].z * aA[n].z; qvA.w += aA[n].w * aA[n].w;
            qvB.x += aB[n].x * aB[n].x; qvB.y += aB[n].y * aB[n].y;
            qvB.z += aB[n].z * aB[n].z; qvB.w += aB[n].w * aB[n].w;
        }
        int cb = cg * 8;
        atomicAdd(&ls[cb + 0], svA.x); atomicAdd(&ls[cb + 1], svA.y);
        atomicAdd(&ls[cb + 2], svA.z); atomicAdd(&ls[cb + 3], svA.w);
        atomicAdd(&ls[cb + 4], svB.x); atomicAdd(&ls[cb + 5], svB.y);
        atomicAdd(&ls[cb + 6], svB.z); atomicAdd(&ls[cb + 7], svB.w);
        atomicAdd(&ls[H + cb + 0], qvA.x); atomicAdd(&ls[H + cb + 1], qvA.y);
        atomicAdd(&ls[H + cb + 2], qvA.z); atomicAdd(&ls[H + cb + 3], qvA.w);
        atomicAdd(&ls[H + cb + 4], qvB.x); atomicAdd(&ls[H + cb + 5], qvB.y);
        atomicAdd(&ls[H + cb + 6], qvB.z); atomicAdd(&ls[H + cb + 7], qvB.w);
    }
    __syncthreads();
    atomicAdd(&stats[tid], ls[tid]);
}

// ---------------- BN finalize into prm slot ----------------
__global__ void k_bn_fin(const float* __restrict__ stats, const float* __restrict__ gamma,
                         const float* __restrict__ beta, float* __restrict__ prm) {
    int c = threadIdx.x;  // 128
    float mean = stats[c] * (1.f / NN);
    float var = stats[H + c] * (1.f / NN) - mean * mean;
    float sc = gamma[c] * rsqrtf(var + 1e-5f);
    prm[c] = sc;
    prm[H + c] = beta[c] - mean * sc;
}

// ---------------- pool: sum of relu(sc*z2+sh) per graph (batch sorted) ----------------
__global__ __launch_bounds__(256) void k_pool(const float* __restrict__ z2, const float* __restrict__ prm,
                                              const int* __restrict__ batch, float* __restrict__ sums,
                                              float* __restrict__ cntf) {
    int tid = threadIdx.x;
    int c = tid & 127, half = tid >> 7;
    float sc = prm[c], sh = prm[H + c];
    int n0 = blockIdx.x * 64 + half * 32;
    float acc = 0.f;
    int curg = -1, runlen = 0;
    for (int i = 0; i < 32; ++i) {
        int n = n0 + i;
        if (n >= NN) break;
        int g = batch[n];
        float v = fmaxf(fmaf(sc, z2[(size_t)n * H + c], sh), 0.f);
        if (g != curg) {
            if (curg >= 0) {
                atomicAdd(&sums[(size_t)curg * H + c], acc);
                if (c == 0) atomicAdd(&cntf[curg], (float)runlen);
            }
            curg = g; acc = v; runlen = 1;
        } else {
            acc += v; runlen++;
        }
    }
    if (curg >= 0) {
        atomicAdd(&sums[(size_t)curg * H + c], acc);
        if (c == 0) atomicAdd(&cntf[curg], (float)runlen);
    }
}

__global__ void k_pool_fin(const float* __restrict__ sums, const float* __restrict__ cntf,
                           float* __restrict__ out) {
    int i = blockIdx.x * blockDim.x + threadIdx.x;  // 65536 = NG*H
    if (i < NG * H) {
        int g = i >> 7;
        out[i] = sums[i] / fmaxf(cntf[g], 1.f);
    }
}

extern "C" void kernel_launch(void* const* d_in, const int* in_sizes, int n_in,
                              void* d_out, int out_size, void* d_ws, size_t ws_size,
                              hipStream_t stream) {
    const float* x      = (const float*)d_in[0];
    const int*   ei     = (const int*)d_in[1];
    const float* ea     = (const float*)d_in[2];
    const int*   batch  = (const int*)d_in[3];
    const float* node_w = (const float*)d_in[4];
    const float* node_b = (const float*)d_in[5];
    const float* edge_w = (const float*)d_in[6];
    const float* edge_b = (const float*)d_in[7];
    const float* w1     = (const float*)d_in[8];
    const float* b1     = (const float*)d_in[9];
    const float* w2     = (const float*)d_in[10];
    const float* b2     = (const float*)d_in[11];
    const float* gamma  = (const float*)d_in[12];
    const float* beta   = (const float*)d_in[13];
    float* out = (float*)d_out;

    char* ws = (char*)d_ws;
    const size_t SZ_H = (size_t)NN * H * 4;  // 51,200,000 B (16B aligned)
    float* X     = (float*)(ws);
    float* Y     = (float*)(ws + SZ_H);
    char*  tail  = ws + 2 * SZ_H;
    float* stats = (float*)(tail);                           // 256 f
    float* prm   = (float*)(tail + 1024);                    // 5*256 f
    float* pool  = (float*)(tail + 1024 + 8192);             // 65536 f
    float* cntf  = (float*)(tail + 1024 + 8192 + 262144);    // 512 f
    char*  itail = tail + 1024 + 8192 + 262144 + 2048;
    int4* erec   = (int4*)(itail);                           // 640000 * 16 B
    int*  deg    = (int*)(itail + (size_t)NE * 16);          // 100352
    int*  ex     = deg + 100352;
    int*  totals = ex + 100352;                              // 128
    int*  boff   = totals + 128;                             // 128
    int*  rowptr = boff + 128;                               // 100352 (incl. NN slot)
    int*  cursor = rowptr + 100352;

    const int* srcp = ei;
    const int* dstp = ei + NE;

    // CSR build (once; reused across layers)
    hipMemsetAsync(deg, 0, 100352 * sizeof(int), stream);
    k_hist<<<2500, 256, 0, stream>>>(dstp, deg);
    k_scan1<<<98, 256, 0, stream>>>(deg, ex, totals);
    k_scan2<<<1, 256, 0, stream>>>(totals, boff);
    k_scan3<<<392, 256, 0, stream>>>(ex, boff, rowptr, cursor);
    k_scatter<<<2500, 256, 0, stream>>>(srcp, dstp, cursor, erec);

    k_prm_id<<<1, 128, 0, stream>>>(prm);
    k_node_proj<<<2048, 256, 0, stream>>>(x, node_w, node_b, X);

    float* hs = X;
    float* ag = Y;
    for (int l = 0; l < NL; ++l) {
        hipMemsetAsync(ag, 0, SZ_H, stream);
        hipMemsetAsync(stats, 0, 256 * sizeof(float), stream);
        k_agg<<<10000, 256, 0, stream>>>(erec, ea, edge_w, edge_b, hs, prm + l * 256, ag);
        k_mlp<<<3125, 256, 0, stream>>>(hs, prm + l * 256, ag,
                                        w1 + (size_t)l * H * H2, b1 + (size_t)l * H2,
                                        w2 + (size_t)l * H2 * H, b2 + (size_t)l * H, stats);
        k_bn_fin<<<1, 128, 0, stream>>>(stats, gamma + (size_t)l * H, beta + (size_t)l * H,
                                        prm + (l + 1) * 256);
        float* tmp = hs; hs = ag; ag = tmp;
    }

    hipMemsetAsync(pool, 0, (NG * H + NG) * sizeof(float), stream);
    k_pool<<<1563, 256, 0, stream>>>(hs, prm + NL * 256, batch, pool, cntf);
    k_pool_fin<<<256, 256, 0, stream>>>(pool, cntf, out);
}

// Round 10
// 2019.238 us; speedup vs baseline: 1.2868x; 1.2868x over previous
//
#include <hip/hip_runtime.h>
#include <hip/hip_bf16.h>

#define NN 100000
#define NE 640000
#define NG 512
#define NIN 64
#define EIN 16
#define H 128
#define H2 256
#define NL 4

#define FMA4(acc, s, wv)                      \
    acc.x = fmaf(s, wv.x, acc.x);             \
    acc.y = fmaf(s, wv.y, acc.y);             \
    acc.z = fmaf(s, wv.z, acc.z);             \
    acc.w = fmaf(s, wv.w, acc.w)

// ---------------- node projection: X = relu(x @ node_w + node_b) ----------------
__global__ __launch_bounds__(256) void k_node_proj(const float* __restrict__ x,
                                                   const float* __restrict__ W,
                                                   const float* __restrict__ b,
                                                   float* __restrict__ h) {
    __shared__ float sW[NIN * H];  // 32 KB
    int tid = threadIdx.x;
    for (int i = tid; i < NIN * H; i += 256) sW[i] = W[i];
    __syncthreads();
    int c = tid & 127, half = tid >> 7;
    for (int node = blockIdx.x * 2 + half; node < NN; node += gridDim.x * 2) {
        const float* xr = x + (size_t)node * NIN;
        float acc = b[c];
#pragma unroll
        for (int k = 0; k < NIN; ++k) acc = fmaf(xr[k], sW[k * H + c], acc);
        h[(size_t)node * H + c] = fmaxf(acc, 0.f);
    }
}

// ---------------- CSR build ----------------
__global__ __launch_bounds__(256) void k_hist(const int* __restrict__ dst, int* __restrict__ deg) {
    int e = blockIdx.x * 256 + threadIdx.x;
    if (e < NE) atomicAdd(&deg[dst[e]], 1);
}

__global__ __launch_bounds__(256) void k_scan1(const int* __restrict__ deg, int* __restrict__ ex,
                                               int* __restrict__ totals) {
    __shared__ int s[256];
    int t = threadIdx.x, b = blockIdx.x;
    int base = b * 1024 + t * 4;
    int v0 = (base + 0 < NN) ? deg[base + 0] : 0;
    int v1 = (base + 1 < NN) ? deg[base + 1] : 0;
    int v2 = (base + 2 < NN) ? deg[base + 2] : 0;
    int v3 = (base + 3 < NN) ? deg[base + 3] : 0;
    int t0 = v0, t1 = t0 + v1, t2 = t1 + v2, tsum = t2 + v3;
    s[t] = tsum;
    __syncthreads();
#pragma unroll
    for (int d = 1; d < 256; d <<= 1) {
        int add = (t >= d) ? s[t - d] : 0;
        __syncthreads();
        s[t] += add;
        __syncthreads();
    }
    int excl = s[t] - tsum;
    ex[base + 0] = excl;
    ex[base + 1] = excl + t0;
    ex[base + 2] = excl + t1;
    ex[base + 3] = excl + t2;
    if (t == 255) totals[b] = s[t];
}

__global__ void k_scan2(const int* __restrict__ totals, int* __restrict__ boff) {
    __shared__ int s[256];
    int t = threadIdx.x;
    int v = (t < 98) ? totals[t] : 0;
    s[t] = v;
    __syncthreads();
#pragma unroll
    for (int d = 1; d < 256; d <<= 1) {
        int add = (t >= d) ? s[t - d] : 0;
        __syncthreads();
        s[t] += add;
        __syncthreads();
    }
    if (t < 98) boff[t] = s[t] - v;
}

__global__ __launch_bounds__(256) void k_scan3(const int* __restrict__ ex, const int* __restrict__ boff,
                                               int* __restrict__ rowptr, int* __restrict__ cursor) {
    int i = blockIdx.x * 256 + threadIdx.x;
    if (i < NN) {
        int r = ex[i] + boff[i >> 10];
        rowptr[i] = r;
        cursor[i] = r;
    }
    if (i == 0) rowptr[NN] = NE;
}

// scatter: erec[p] = (src, dst, eid, 0) — one 16B record per edge, dst-sorted
__global__ __launch_bounds__(256) void k_scatter(const int* __restrict__ src,
                                                 const int* __restrict__ dst,
                                                 int* __restrict__ cursor,
                                                 int4* __restrict__ erec) {
    int e = blockIdx.x * 256 + threadIdx.x;
    if (e < NE) {
        int d = dst[e];
        int p = atomicAdd(&cursor[d], 1);
        erec[p] = make_int4(src[e], d, e, 0);
    }
}

__global__ void k_prm_id(float* __restrict__ prm) {
    int c = threadIdx.x;  // 128
    prm[c] = 1.f;
    prm[H + c] = 0.f;
}

// ------- edge-parallel aggregate over dst-sorted records; flush on dst change -------
__global__ __launch_bounds__(256) void k_agg(const int4* __restrict__ erec,
                                             const float* __restrict__ ea,
                                             const float* __restrict__ We,
                                             const float* __restrict__ be,
                                             const float* __restrict__ hsrc,
                                             const float* __restrict__ prm,
                                             float* __restrict__ agg) {
    int tid = threadIdx.x;
    int c = tid & 127, grp = tid >> 7;
    float wcol[EIN];
#pragma unroll
    for (int k = 0; k < EIN; ++k) wcol[k] = We[k * H + c];
    float bec = be[c], sc = prm[c], sh = prm[H + c];
    const float4* ea4 = (const float4*)ea;
    int base = (blockIdx.x * 2 + grp) * 32;  // 10000 blocks * 2 groups * 32 edges = NE
    int cur = erec[base].y;
    float acc = 0.f;
#pragma unroll
    for (int i0 = 0; i0 < 32; i0 += 4) {
        int4 r0 = erec[base + i0 + 0];
        int4 r1 = erec[base + i0 + 1];
        int4 r2 = erec[base + i0 + 2];
        int4 r3 = erec[base + i0 + 3];
        float hv0 = hsrc[(size_t)r0.x * H + c];
        float hv1 = hsrc[(size_t)r1.x * H + c];
        float hv2 = hsrc[(size_t)r2.x * H + c];
        float hv3 = hsrc[(size_t)r3.x * H + c];
        float4 a0 = ea4[(size_t)r0.z * 4 + 0], a1 = ea4[(size_t)r0.z * 4 + 1],
               a2 = ea4[(size_t)r0.z * 4 + 2], a3 = ea4[(size_t)r0.z * 4 + 3];
        float4 b0 = ea4[(size_t)r1.z * 4 + 0], b1 = ea4[(size_t)r1.z * 4 + 1],
               b2 = ea4[(size_t)r1.z * 4 + 2], b3 = ea4[(size_t)r1.z * 4 + 3];
        float4 c0 = ea4[(size_t)r2.z * 4 + 0], c1 = ea4[(size_t)r2.z * 4 + 1],
               c2 = ea4[(size_t)r2.z * 4 + 2], c3 = ea4[(size_t)r2.z * 4 + 3];
        float4 d0 = ea4[(size_t)r3.z * 4 + 0], d1 = ea4[(size_t)r3.z * 4 + 1],
               d2 = ea4[(size_t)r3.z * 4 + 2], d3 = ea4[(size_t)r3.z * 4 + 3];

#define EPROJ(pp, e0, e1, e2, e3)                                              \
        {                                                                      \
            pp = bec;                                                          \
            pp = fmaf(e0.x, wcol[0], pp);  pp = fmaf(e0.y, wcol[1], pp);       \
            pp = fmaf(e0.z, wcol[2], pp);  pp = fmaf(e0.w, wcol[3], pp);       \
            pp = fmaf(e1.x, wcol[4], pp);  pp = fmaf(e1.y, wcol[5], pp);       \
            pp = fmaf(e1.z, wcol[6], pp);  pp = fmaf(e1.w, wcol[7], pp);       \
            pp = fmaf(e2.x, wcol[8], pp);  pp = fmaf(e2.y, wcol[9], pp);       \
            pp = fmaf(e2.z, wcol[10], pp); pp = fmaf(e2.w, wcol[11], pp);      \
            pp = fmaf(e3.x, wcol[12], pp); pp = fmaf(e3.y, wcol[13], pp);      \
            pp = fmaf(e3.z, wcol[14], pp); pp = fmaf(e3.w, wcol[15], pp);      \
            pp = fmaxf(pp, 0.f);                                               \
        }
        float p0, p1, p2, p3;
        EPROJ(p0, a0, a1, a2, a3)
        EPROJ(p1, b0, b1, b2, b3)
        EPROJ(p2, c0, c1, c2, c3)
        EPROJ(p3, d0, d1, d2, d3)
#undef EPROJ
        float m0 = fmaxf(fmaxf(fmaf(sc, hv0, sh), 0.f) + p0, 0.f);
        float m1 = fmaxf(fmaxf(fmaf(sc, hv1, sh), 0.f) + p1, 0.f);
        float m2 = fmaxf(fmaxf(fmaf(sc, hv2, sh), 0.f) + p2, 0.f);
        float m3 = fmaxf(fmaxf(fmaf(sc, hv3, sh), 0.f) + p3, 0.f);
        if (r0.y != cur) { atomicAdd(&agg[(size_t)cur * H + c], acc); acc = 0.f; cur = r0.y; }
        acc += m0;
        if (r1.y != cur) { atomicAdd(&agg[(size_t)cur * H + c], acc); acc = 0.f; cur = r1.y; }
        acc += m1;
        if (r2.y != cur) { atomicAdd(&agg[(size_t)cur * H + c], acc); acc = 0.f; cur = r2.y; }
        acc += m2;
        if (r3.y != cur) { atomicAdd(&agg[(size_t)cur * H + c], acc); acc = 0.f; cur = r3.y; }
        acc += m3;
    }
    atomicAdd(&agg[(size_t)cur * H + c], acc);
}

// ---- MLP per 32-node tile (round-2 c64/c32 layout + 2-deep weight prefetch) ----
__global__ __launch_bounds__(256) void k_mlp(const float* __restrict__ hsrc,
                                             const float* __restrict__ prm,
                                             float* __restrict__ agg,  // in: agg, out: z2
                                             const float* __restrict__ w1,
                                             const float* __restrict__ b1,
                                             const float* __restrict__ w2,
                                             const float* __restrict__ b2,
                                             float* __restrict__ stats) {
    __shared__ float4 sz4[32 * 32];   // 16 KB  [node][32 f4]
    __shared__ float4 st4[32 * 64];   // 32 KB  [node][64 f4]
    __shared__ float ls[2 * H];       // 1 KB
    int tid = threadIdx.x;
    int base = blockIdx.x * 32;  // 3125 * 32 == 100000
    ls[tid] = 0.f;

    // phase 1: z = relu(sc*h+sh) + agg -> LDS
    const float4* X4 = (const float4*)hsrc;
    const float4* A4 = (const float4*)agg;
#pragma unroll
    for (int it = 0; it < 4; ++it) {
        int chunk = tid + it * 256;  // 0..1023
        int n = chunk >> 5;
        int c4 = chunk & 31;
        const float4 sc4 = *(const float4*)&prm[c4 * 4];
        const float4 sh4 = *(const float4*)&prm[H + c4 * 4];
        size_t gi = (size_t)(base + n) * 32 + c4;
        float4 hv = X4[gi], av = A4[gi];
        float4 z;
        z.x = fmaxf(fmaf(sc4.x, hv.x, sh4.x), 0.f) + av.x;
        z.y = fmaxf(fmaf(sc4.y, hv.y, sh4.y), 0.f) + av.y;
        z.z = fmaxf(fmaf(sc4.z, hv.z, sh4.z), 0.f) + av.z;
        z.w = fmaxf(fmaf(sc4.w, hv.w, sh4.w), 0.f) + av.w;
        sz4[chunk] = z;
    }
    __syncthreads();

    // phase 2: t = relu(z @ w1 + b1). thread: f4-col c64 (4 cols), 8 nodes; prefetched weights
    {
        int c64 = tid & 63, ng = tid >> 6;
        const float4* W14 = (const float4*)w1;  // [128][64] f4
        float4 acc[8];
        float4 bv = ((const float4*)b1)[c64];
#pragma unroll
        for (int n = 0; n < 8; ++n) acc[n] = bv;
        float4 wc0 = W14[0 * 64 + c64], wc1 = W14[1 * 64 + c64],
               wc2 = W14[2 * 64 + c64], wc3 = W14[3 * 64 + c64];
        for (int k0 = 0; k0 < H; k0 += 4) {
            int kn = (k0 + 4 < H) ? (k0 + 4) : 0;  // clamp: last iter redundantly reloads row 0
            float4 wn0 = W14[(kn + 0) * 64 + c64];
            float4 wn1 = W14[(kn + 1) * 64 + c64];
            float4 wn2 = W14[(kn + 2) * 64 + c64];
            float4 wn3 = W14[(kn + 3) * 64 + c64];
#pragma unroll
            for (int n = 0; n < 8; ++n) {
                float4 zv = sz4[(ng * 8 + n) * 32 + (k0 >> 2)];
                FMA4(acc[n], zv.x, wc0);
                FMA4(acc[n], zv.y, wc1);
                FMA4(acc[n], zv.z, wc2);
                FMA4(acc[n], zv.w, wc3);
            }
            wc0 = wn0; wc1 = wn1; wc2 = wn2; wc3 = wn3;
        }
#pragma unroll
        for (int n = 0; n < 8; ++n) {
            float4 r;
            r.x = fmaxf(acc[n].x, 0.f); r.y = fmaxf(acc[n].y, 0.f);
            r.z = fmaxf(acc[n].z, 0.f); r.w = fmaxf(acc[n].w, 0.f);
            st4[(ng * 8 + n) * 64 + c64] = r;
        }
    }
    __syncthreads();

    // phase 3: z2 = t @ w2 + b2. thread: f4-col c32 (4 cols), 4 nodes; prefetched weights
    {
        int c32 = tid & 31, ng = tid >> 5;
        const float4* W24 = (const float4*)w2;  // [256][32] f4
        float4 acc2[4];
        float4 bv = ((const float4*)b2)[c32];
#pragma unroll
        for (int n = 0; n < 4; ++n) acc2[n] = bv;
        float4 uc0 = W24[0 * 32 + c32], uc1 = W24[1 * 32 + c32],
               uc2 = W24[2 * 32 + c32], uc3 = W24[3 * 32 + c32];
        for (int j0 = 0; j0 < H2; j0 += 4) {
            int jn = (j0 + 4 < H2) ? (j0 + 4) : 0;
            float4 un0 = W24[(jn + 0) * 32 + c32];
            float4 un1 = W24[(jn + 1) * 32 + c32];
            float4 un2 = W24[(jn + 2) * 32 + c32];
            float4 un3 = W24[(jn + 3) * 32 + c32];
#pragma unroll
            for (int n = 0; n < 4; ++n) {
                float4 tv = st4[(ng * 4 + n) * 64 + (j0 >> 2)];
                FMA4(acc2[n], tv.x, uc0);
                FMA4(acc2[n], tv.y, uc1);
                FMA4(acc2[n], tv.z, uc2);
                FMA4(acc2[n], tv.w, uc3);
            }
            uc0 = un0; uc1 = un1; uc2 = un2; uc3 = un3;
        }
        float4* O4 = (float4*)agg;
        float4 sv = {0, 0, 0, 0}, qv = {0, 0, 0, 0};
#pragma unroll
        for (int n = 0; n < 4; ++n) {
            O4[(size_t)(base + ng * 4 + n) * 32 + c32] = acc2[n];
            sv.x += acc2[n].x; sv.y += acc2[n].y; sv.z += acc2[n].z; sv.w += acc2[n].w;
            qv.x += acc2[n].x * acc2[n].x; qv.y += acc2[n].y * acc2[n].y;
            qv.z += acc2[n].z * acc2[n].z; qv.w += acc2[n].w * acc2[n].w;
        }
        int cb = c32 * 4;
        atomicAdd(&ls[cb + 0], sv.x); atomicAdd(&ls[cb + 1], sv.y);
        atomicAdd(&ls[cb + 2], sv.z); atomicAdd(&ls[cb + 3], sv.w);
        atomicAdd(&ls[H + cb + 0], qv.x); atomicAdd(&ls[H + cb + 1], qv.y);
        atomicAdd(&ls[H + cb + 2], qv.z); atomicAdd(&ls[H + cb + 3], qv.w);
    }
    __syncthreads();
    atomicAdd(&stats[tid], ls[tid]);
}

// ---------------- BN finalize into prm slot ----------------
__global__ void k_bn_fin(const float* __restrict__ stats, const float* __restrict__ gamma,
                         const float* __restrict__ beta, float* __restrict__ prm) {
    int c = threadIdx.x;  // 128
    float mean = stats[c] * (1.f / NN);
    float var = stats[H + c] * (1.f / NN) - mean * mean;
    float sc = gamma[c] * rsqrtf(var + 1e-5f);
    prm[c] = sc;
    prm[H + c] = beta[c] - mean * sc;
}

// ---------------- pool: sum of relu(sc*z2+sh) per graph (batch sorted) ----------------
__global__ __launch_bounds__(256) void k_pool(const float* __restrict__ z2, const float* __restrict__ prm,
                                              const int* __restrict__ batch, float* __restrict__ sums,
                                              float* __restrict__ cntf) {
    int tid = threadIdx.x;
    int c = tid & 127, half = tid >> 7;
    float sc = prm[c], sh = prm[H + c];
    int n0 = blockIdx.x * 64 + half * 32;
    float acc = 0.f;
    int curg = -1, runlen = 0;
    for (int i = 0; i < 32; ++i) {
        int n = n0 + i;
        if (n >= NN) break;
        int g = batch[n];
        float v = fmaxf(fmaf(sc, z2[(size_t)n * H + c], sh), 0.f);
        if (g != curg) {
            if (curg >= 0) {
                atomicAdd(&sums[(size_t)curg * H + c], acc);
                if (c == 0) atomicAdd(&cntf[curg], (float)runlen);
            }
            curg = g; acc = v; runlen = 1;
        } else {
            acc += v; runlen++;
        }
    }
    if (curg >= 0) {
        atomicAdd(&sums[(size_t)curg * H + c], acc);
        if (c == 0) atomicAdd(&cntf[curg], (float)runlen);
    }
}

__global__ void k_pool_fin(const float* __restrict__ sums, const float* __restrict__ cntf,
                           float* __restrict__ out) {
    int i = blockIdx.x * blockDim.x + threadIdx.x;  // 65536 = NG*H
    if (i < NG * H) {
        int g = i >> 7;
        out[i] = sums[i] / fmaxf(cntf[g], 1.f);
    }
}

extern "C" void kernel_launch(void* const* d_in, const int* in_sizes, int n_in,
                              void* d_out, int out_size, void* d_ws, size_t ws_size,
                              hipStream_t stream) {
    const float* x      = (const float*)d_in[0];
    const int*   ei     = (const int*)d_in[1];
    const float* ea     = (const float*)d_in[2];
    const int*   batch  = (const int*)d_in[3];
    const float* node_w = (const float*)d_in[4];
    const float* node_b = (const float*)d_in[5];
    const float* edge_w = (const float*)d_in[6];
    const float* edge_b = (const float*)d_in[7];
    const float* w1     = (const float*)d_in[8];
    const float* b1     = (const float*)d_in[9];
    const float* w2     = (const float*)d_in[10];
    const float* b2     = (const float*)d_in[11];
    const float* gamma  = (const float*)d_in[12];
    const float* beta   = (const float*)d_in[13];
    float* out = (float*)d_out;

    char* ws = (char*)d_ws;
    const size_t SZ_H = (size_t)NN * H * 4;  // 51,200,000 B (16B aligned)
    float* X     = (float*)(ws);
    float* Y     = (float*)(ws + SZ_H);
    char*  tail  = ws + 2 * SZ_H;
    float* stats = (float*)(tail);                           // 256 f
    float* prm   = (float*)(tail + 1024);                    // 5*256 f
    float* pool  = (float*)(tail + 1024 + 8192);             // 65536 f
    float* cntf  = (float*)(tail + 1024 + 8192 + 262144);    // 512 f
    char*  itail = tail + 1024 + 8192 + 262144 + 2048;
    int4* erec   = (int4*)(itail);                           // 640000 * 16 B
    int*  deg    = (int*)(itail + (size_t)NE * 16);          // 100352
    int*  ex     = deg + 100352;
    int*  totals = ex + 100352;                              // 128
    int*  boff   = totals + 128;                             // 128
    int*  rowptr = boff + 128;                               // 100352 (incl. NN slot)
    int*  cursor = rowptr + 100352;

    const int* srcp = ei;
    const int* dstp = ei + NE;

    // CSR build (once; reused across layers)
    hipMemsetAsync(deg, 0, 100352 * sizeof(int), stream);
    k_hist<<<2500, 256, 0, stream>>>(dstp, deg);
    k_scan1<<<98, 256, 0, stream>>>(deg, ex, totals);
    k_scan2<<<1, 256, 0, stream>>>(totals, boff);
    k_scan3<<<392, 256, 0, stream>>>(ex, boff, rowptr, cursor);
    k_scatter<<<2500, 256, 0, stream>>>(srcp, dstp, cursor, erec);

    k_prm_id<<<1, 128, 0, stream>>>(prm);
    k_node_proj<<<2048, 256, 0, stream>>>(x, node_w, node_b, X);

    float* hs = X;
    float* ag = Y;
    for (int l = 0; l < NL; ++l) {
        hipMemsetAsync(ag, 0, SZ_H, stream);
        hipMemsetAsync(stats, 0, 256 * sizeof(float), stream);
        k_agg<<<10000, 256, 0, stream>>>(erec, ea, edge_w, edge_b, hs, prm + l * 256, ag);
        k_mlp<<<3125, 256, 0, stream>>>(hs, prm + l * 256, ag,
                                        w1 + (size_t)l * H * H2, b1 + (size_t)l * H2,
                                        w2 + (size_t)l * H2 * H, b2 + (size_t)l * H, stats);
        k_bn_fin<<<1, 128, 0, stream>>>(stats, gamma + (size_t)l * H, beta + (size_t)l * H,
                                        prm + (l + 1) * 256);
        float* tmp = hs; hs = ag; ag = tmp;
    }

    hipMemsetAsync(pool, 0, (NG * H + NG) * sizeof(float), stream);
    k_pool<<<1563, 256, 0, stream>>>(hs, prm + NL * 256, batch, pool, cntf);
    k_pool_fin<<<256, 256, 0, stream>>>(pool, cntf, out);
}